// Round 5
// baseline (373.018 us; speedup 1.0000x reference)
//
#include <hip/hip_runtime.h>

typedef __attribute__((ext_vector_type(8))) short short8;
typedef __attribute__((ext_vector_type(4))) float floatx4;

// int-bridge casts (generic->AS1/AS3): LDS generic addr low 32 bits = LDS offset
#define AS1(p) ((const __attribute__((address_space(1))) void*)(uintptr_t)(p))
#define AS3(p) ((__attribute__((address_space(3))) void*)(unsigned int)(uintptr_t)(p))

__device__ __forceinline__ unsigned short f2bf(float f) {
    union { float f; unsigned int u; } v; v.f = f;
    unsigned int u = v.u;
    unsigned int r = (u + 0x7FFFu + ((u >> 16) & 1u)) >> 16;
    return (unsigned short)r;
}

__device__ __forceinline__ int pk_bf16(float a, float b) {
#if __has_builtin(__builtin_amdgcn_cvt_pk_bf16_f32)
    auto r = __builtin_amdgcn_cvt_pk_bf16_f32(a, b);
    int out; __builtin_memcpy(&out, &r, sizeof(int)); return out;
#else
    return (int)f2bf(a) | ((int)f2bf(b) << 16);
#endif
}

// ---------------- convert x (fp32 -> bf16), 4 elems/thread ----------------
__global__ __launch_bounds__(256) void cvt_x(const float* __restrict__ src,
                                             unsigned short* __restrict__ dst, int n4) {
    int i = blockIdx.x * blockDim.x + threadIdx.x;
    if (i < n4) {
        float4 v = ((const float4*)src)[i];
        int2 o = {pk_bf16(v.x, v.y), pk_bf16(v.z, v.w)};
        ((int2*)dst)[i] = o;
    }
}

// ------------- transpose + convert: src[R][C] fp32 -> dst[C][R] bf16 -------------
__global__ __launch_bounds__(256) void transpose_bf16(const float* __restrict__ src,
                                                      unsigned short* __restrict__ dst,
                                                      int R, int C) {
    __shared__ float tile[32][33];
    int c0 = blockIdx.x * 32, r0 = blockIdx.y * 32;
    int tc = threadIdx.x & 31, tr = (threadIdx.x >> 5) * 4;
#pragma unroll
    for (int i = 0; i < 4; ++i)
        tile[tr + i][tc] = src[(size_t)(r0 + tr + i) * C + c0 + tc];
    __syncthreads();
#pragma unroll
    for (int i = 0; i < 4; ++i)
        dst[(size_t)(c0 + tr + i) * R + r0 + tc] = f2bf(tile[tc][tr + i]);
}

// -------------- 128x256-tile multi-block-per-CU bf16 MFMA GEMM --------------
// (unchanged from round 4 -- see comments there; ~830 TF plateau)
template <bool OUT_BF16>
__global__ __launch_bounds__(256, 2) void gemm_bt128(const unsigned short* __restrict__ A,
                                                     const unsigned short* __restrict__ Bt,
                                                     void* __restrict__ Cout,
                                                     int M, int N, int K, int nbx) {
    __shared__ unsigned short Asm[2][128 * 32];
    __shared__ unsigned short Bsm[2][256 * 32];

    const int tid = threadIdx.x;
    const int wn = tid >> 6, lane = tid & 63, quad = lane >> 4, l15 = lane & 15;

    const int nwg = (int)gridDim.x;
    const int q8 = nwg >> 3;
    const int wgid = (int)blockIdx.x;
    const int swz = (wgid & 7) * q8 + (wgid >> 3);
    const int bm = (swz / nbx) * 128;
    const int bn = (swz % nbx) * 256;

    floatx4 acc[8][4];
    const floatx4 z = {0.f, 0.f, 0.f, 0.f};
#pragma unroll
    for (int mi = 0; mi < 8; ++mi)
#pragma unroll
        for (int ni = 0; ni < 4; ++ni) acc[mi][ni] = z;

    const int dA0 = tid, dA1 = tid + 256;
    const int rA0 = dA0 >> 2, cA0 = ((dA0 & 3) ^ ((dA0 >> 3) & 3)) * 8;
    const int rA1 = dA1 >> 2, cA1 = ((dA1 & 3) ^ ((dA1 >> 3) & 3)) * 8;
    const unsigned short* Asrc0 = A + (size_t)(bm + rA0) * K + cA0;
    const unsigned short* Asrc1 = A + (size_t)(bm + rA1) * K + cA1;
    const unsigned short* Bsrc[4];
    int dB[4];
#pragma unroll
    for (int j = 0; j < 4; ++j) {
        dB[j] = tid + j * 256;
        const int r = dB[j] >> 2, c = ((dB[j] & 3) ^ ((dB[j] >> 3) & 3)) * 8;
        Bsrc[j] = Bt + (size_t)(bn + r) * K + c;
    }

    const int NT = K >> 5;

    auto stage = [&](int t) {
        const int s = t & 1, ko = t * 32;
        __builtin_amdgcn_global_load_lds(AS1(Asrc0 + ko), AS3(&Asm[s][dA0 * 8]), 16, 0, 0);
        __builtin_amdgcn_global_load_lds(AS1(Asrc1 + ko), AS3(&Asm[s][dA1 * 8]), 16, 0, 0);
#pragma unroll
        for (int j = 0; j < 4; ++j)
            __builtin_amdgcn_global_load_lds(AS1(Bsrc[j] + ko), AS3(&Bsm[s][dB[j] * 8]), 16, 0, 0);
    };

    const int qc = (quad ^ ((l15 >> 1) & 3)) * 8;
    const int brow = wn * 64 + l15;

    stage(0);
    asm volatile("s_waitcnt vmcnt(0)" ::: "memory");
    __builtin_amdgcn_s_barrier();

    for (int t = 0; t < NT; ++t) {
        const int s = t & 1;
        const unsigned short* Ap = Asm[s];
        const unsigned short* Bp = Bsm[s];
        if (t + 1 < NT) stage(t + 1);

        short8 b[4], a0[4], a1[4];
#pragma unroll
        for (int ni = 0; ni < 4; ++ni)
            b[ni] = *(const short8*)&Bp[(brow + ni * 16) * 32 + qc];
#pragma unroll
        for (int mi = 0; mi < 4; ++mi)
            a0[mi] = *(const short8*)&Ap[(mi * 16 + l15) * 32 + qc];
#pragma unroll
        for (int mi = 0; mi < 4; ++mi)
            a1[mi] = *(const short8*)&Ap[(64 + mi * 16 + l15) * 32 + qc];

        __builtin_amdgcn_s_setprio(1);
#pragma unroll
        for (int mi = 0; mi < 4; ++mi)
#pragma unroll
            for (int ni = 0; ni < 4; ++ni)
                acc[mi][ni] = __builtin_amdgcn_mfma_f32_16x16x32_bf16(b[ni], a0[mi], acc[mi][ni], 0, 0, 0);
#pragma unroll
        for (int mi = 0; mi < 4; ++mi)
#pragma unroll
            for (int ni = 0; ni < 4; ++ni)
                acc[4 + mi][ni] = __builtin_amdgcn_mfma_f32_16x16x32_bf16(b[ni], a1[mi], acc[4 + mi][ni], 0, 0, 0);
        __builtin_amdgcn_s_setprio(0);

        asm volatile("s_waitcnt vmcnt(0)" ::: "memory");
        __builtin_amdgcn_s_barrier();
    }

#pragma unroll
    for (int mi = 0; mi < 8; ++mi) {
        const size_t row = (size_t)(bm + mi * 16 + l15);
#pragma unroll
        for (int ni = 0; ni < 4; ++ni) {
            const size_t col = (size_t)(bn + wn * 64 + ni * 16 + quad * 4);
            if (OUT_BF16) {
                int2 val = {pk_bf16(acc[mi][ni][0], acc[mi][ni][1]),
                            pk_bf16(acc[mi][ni][2], acc[mi][ni][3])};
                *(int2*)((unsigned short*)Cout + row * N + col) = val;
            } else {
                *(float4*)((float*)Cout + row * N + col) = *(const float4*)&acc[mi][ni];
            }
        }
    }
}

// ---------------- sliding-window flash attention (S^T, 32q/wave) ----------------
// Grid (32 q-blocks of 128, 64 b*h). Block: 4 waves; wave w owns 32 queries.
// Wave-pair p = w>>1 active in chunks [p, p+4] of 6 (83% busy).
// S^T = K.Q^T; softmax stats per-lane (q=l15); P->A-frag via ds_bpermute.
// ROUND 5: (1) K staged via global_load_lds + XOR chunk swizzle (64-stride,
// GEMM-proven conflict-free; removes K reg-staging + 2 ds_writes + 8 VGPR);
// __syncthreads' implicit vmcnt(0)/lgkmcnt(0) drain orders the DMA (issued a
// full iteration earlier -> no stall).  (2) 4 blocks/CU (34.4 KiB LDS, VGPR
// trimmed under 128 by loading vf AFTER softmax).  (3) setprio around MFMA.
__global__ __launch_bounds__(256, 4) void attn_swin(const unsigned short* __restrict__ qkv,
                                                    unsigned short* __restrict__ attn_out) {
    __shared__ unsigned short Klds[2][64 * 64];   // XOR-swizzled, DMA-staged
    __shared__ unsigned short Vtl[2][64 * 72];    // V^T, stride 72 (2-way alias free)

    const int blk = blockIdx.x, bh = blockIdx.y;
    const int b = bh >> 4, h = bh & 15;
    const int tid = threadIdx.x;
    const int wave = tid >> 6, lane = tid & 63, quad = lane >> 4, l15 = lane & 15;
    const int pair = wave >> 1;            // diagonal band of the wave-pair
    const int qoff = (wave & 1) * 32;      // offset within the pair's 64-q band
    const int qi_base = blk * 128 + wave * 32;
    const size_t seqbase = (size_t)b * 4096;

    // Q fragments hoisted once (A-layout == B-layout of Q^T)
    short8 qf[2][2];
#pragma unroll
    for (int qt = 0; qt < 2; ++qt)
#pragma unroll
        for (int ks = 0; ks < 2; ++ks)
            qf[qt][ks] = *(const short8*)(qkv + (seqbase + qi_base + qt * 16 + l15) * 3072
                                          + h * 64 + ks * 32 + quad * 8);

    floatx4 o[2][4];  // [qt][dt]: lane holds O[q=qt*16+l15][d=dt*16+quad*4+r]
    const floatx4 z = {0.f, 0.f, 0.f, 0.f};
    float m_run[2], l_run[2];
#pragma unroll
    for (int qt = 0; qt < 2; ++qt) {
#pragma unroll
        for (int dt = 0; dt < 4; ++dt) o[qt][dt] = z;
        m_run[qt] = -1.0e30f; l_run[qt] = 0.f;
    }

    const int kwin0 = blk * 128 - 256;
    const int c0 = (blk >= 2) ? 0 : (4 - 2 * blk);
    const int cLo = pair, cHi = pair + 4;
    const int sv_key = tid & 63, sv_dg = (tid >> 6) * 16;
    const float SC = 0.18033688f;  // dh^-0.5 * log2(e)

    // K staging geometry: tile 64 keys x 64 d = 512 16B-chunks; thread owns
    // chunks tid, tid+256.  LDS (row,pos) holds global chunk pos ^ (row&7).
    const int kd0 = tid, kd1 = tid + 256;
    const int kr0 = kd0 >> 3, kc0s = ((kd0 & 7) ^ ((kd0 >> 3) & 7)) * 8;
    const int kr1 = kd1 >> 3, kc1s = ((kd1 & 7) ^ ((kd1 >> 3) & 7)) * 8;
    // kf read swizzle: global chunk (ks*4+quad) of row key -> pos = chunk^(l15&7)
    const int kch[2] = {((0 + quad) ^ (l15 & 7)) * 8, ((4 + quad) ^ (l15 & 7)) * 8};

    // bpermute lane addressing: src lane = (quad&1)*32 + (t>>1)*16 + l15
    const int addrA = (((quad & 1) << 5) + l15) << 2;
    const int addrB = addrA + 64;
    const bool hiq = quad >= 2;

    auto stage_k = [&](int k0, int buf) {
        const unsigned short* s0 = qkv + (seqbase + k0 + kr0) * 3072 + 1024 + h * 64 + kc0s;
        const unsigned short* s1 = qkv + (seqbase + k0 + kr1) * 3072 + 1024 + h * 64 + kc1s;
        __builtin_amdgcn_global_load_lds(AS1(s0), AS3(&Klds[buf][kd0 * 8]), 16, 0, 0);
        __builtin_amdgcn_global_load_lds(AS1(s1), AS3(&Klds[buf][kd1 * 8]), 16, 0, 0);
    };

    int4 vreg[2];
    auto load_v = [&](int k0) {
        const int4* sv = (const int4*)(qkv + (seqbase + k0 + sv_key) * 3072 + 2048 + h * 64 + sv_dg);
        vreg[0] = sv[0]; vreg[1] = sv[1];
    };
    auto write_v = [&](int buf) {
        union { unsigned short s[16]; int4 q[2]; } t;
        t.q[0] = vreg[0]; t.q[1] = vreg[1];
#pragma unroll
        for (int i = 0; i < 16; ++i) Vtl[buf][(sv_dg + i) * 72 + sv_key] = t.s[i];
    };

    stage_k(kwin0 + c0 * 64, 0);   // == key 0 for clipped blocks
    load_v(kwin0 + c0 * 64);
    write_v(0);

    for (int c = c0; c < 6; ++c) {
        const int buf = (c - c0) & 1;
        __syncthreads();   // implicit vmcnt(0)+lgkmcnt(0): K-DMA + V-writes of this buf done
        if (c < 5) {       // prefetch overlaps compute
            stage_k(kwin0 + (c + 1) * 64, buf ^ 1);
            load_v(kwin0 + (c + 1) * 64);
        }

        if (c >= cLo && c <= cHi) {
#pragma unroll
            for (int qt = 0; qt < 2; ++qt) {
                // ---- S^T = K.Q^T (kf transient per qt to cap VGPR) ----
                floatx4 sT[4];
#pragma unroll
                for (int ni = 0; ni < 4; ++ni) sT[ni] = z;
                __builtin_amdgcn_s_setprio(1);
#pragma unroll
                for (int ks = 0; ks < 2; ++ks) {
#pragma unroll
                    for (int ni = 0; ni < 4; ++ni) {
                        short8 kf = *(const short8*)&Klds[buf][(ni * 16 + l15) * 64 + kch[ks]];
                        sT[ni] = __builtin_amdgcn_mfma_f32_16x16x32_bf16(kf, qf[qt][ks], sT[ni], 0, 0, 0);
                    }
                }
                __builtin_amdgcn_s_setprio(0);

                // ---- mask diagonal chunks (key j = ni*16+quad*4+r, query i64) ----
                const int i64 = qoff + qt * 16 + l15;
                if (c == cLo) {            // valid iff j >= i64+1
#pragma unroll
                    for (int ni = 0; ni < 4; ++ni) {
                        int jb = ni * 16 + quad * 4;
#pragma unroll
                        for (int r = 0; r < 4; ++r)
                            if (jb + r < i64 + 1) sT[ni][r] = -3.0e38f;
                    }
                } else if (c == cHi) {     // valid iff j <= i64
#pragma unroll
                    for (int ni = 0; ni < 4; ++ni) {
                        int jb = ni * 16 + quad * 4;
#pragma unroll
                        for (int r = 0; r < 4; ++r)
                            if (jb + r > i64) sT[ni][r] = -3.0e38f;
                    }
                }

                // ---- online softmax (log2 domain, per-lane stats) ----
                float mx = -3.0e38f;
#pragma unroll
                for (int ni = 0; ni < 4; ++ni)
#pragma unroll
                    for (int r = 0; r < 4; ++r) mx = fmaxf(mx, sT[ni][r]);
                mx = fmaxf(mx, __shfl_xor(mx, 16));
                mx = fmaxf(mx, __shfl_xor(mx, 32));
                float mn = fmaxf(m_run[qt], mx * SC);
                float alpha = __builtin_amdgcn_exp2f(m_run[qt] - mn);
                m_run[qt] = mn;

                float ls = 0.f;
                int Pk[4][2];
#pragma unroll
                for (int ni = 0; ni < 4; ++ni) {
                    float p0 = __builtin_amdgcn_exp2f(fmaf(sT[ni][0], SC, -mn));
                    float p1 = __builtin_amdgcn_exp2f(fmaf(sT[ni][1], SC, -mn));
                    float p2 = __builtin_amdgcn_exp2f(fmaf(sT[ni][2], SC, -mn));
                    float p3 = __builtin_amdgcn_exp2f(fmaf(sT[ni][3], SC, -mn));
                    ls += (p0 + p1) + (p2 + p3);
                    Pk[ni][0] = pk_bf16(p0, p1);
                    Pk[ni][1] = pk_bf16(p2, p3);
                }
                ls += __shfl_xor(ls, 16);
                ls += __shfl_xor(ls, 32);
                l_run[qt] = l_run[qt] * alpha + ls;
#pragma unroll
                for (int dt = 0; dt < 4; ++dt)
#pragma unroll
                    for (int r = 0; r < 4; ++r) o[qt][dt][r] *= alpha;

                // ---- V^T fragments (loaded late: shrinks sT/vf live overlap) ----
                short8 vf[4][2];
#pragma unroll
                for (int dt = 0; dt < 4; ++dt)
#pragma unroll
                    for (int ks = 0; ks < 2; ++ks)
                        vf[dt][ks] = *(const short8*)&Vtl[buf][(dt * 16 + l15) * 72 + ks * 32 + quad * 8];

                // ---- quad-permute P (C-layout) -> A-frag, then PV ----
#pragma unroll
                for (int ks = 0; ks < 2; ++ks) {
                    int a0 = __builtin_amdgcn_ds_bpermute(addrA, Pk[2 * ks][0]);
                    int b0 = __builtin_amdgcn_ds_bpermute(addrA, Pk[2 * ks + 1][0]);
                    int a1 = __builtin_amdgcn_ds_bpermute(addrA, Pk[2 * ks][1]);
                    int b1 = __builtin_amdgcn_ds_bpermute(addrA, Pk[2 * ks + 1][1]);
                    int a2 = __builtin_amdgcn_ds_bpermute(addrB, Pk[2 * ks][0]);
                    int b2 = __builtin_amdgcn_ds_bpermute(addrB, Pk[2 * ks + 1][0]);
                    int a3 = __builtin_amdgcn_ds_bpermute(addrB, Pk[2 * ks][1]);
                    int b3 = __builtin_amdgcn_ds_bpermute(addrB, Pk[2 * ks + 1][1]);
                    union { int i[4]; short8 v; } u;
                    u.i[0] = hiq ? b0 : a0;
                    u.i[1] = hiq ? b1 : a1;
                    u.i[2] = hiq ? b2 : a2;
                    u.i[3] = hiq ? b3 : a3;
                    __builtin_amdgcn_s_setprio(1);
#pragma unroll
                    for (int dt = 0; dt < 4; ++dt)
                        o[qt][dt] = __builtin_amdgcn_mfma_f32_16x16x32_bf16(vf[dt][ks], u.v, o[qt][dt], 0, 0, 0);
                    __builtin_amdgcn_s_setprio(0);
                }
            }
        }

        if (c < 5) write_v(buf ^ 1);
    }

    // ---- epilogue ----
#pragma unroll
    for (int qt = 0; qt < 2; ++qt) {
        float rl = __builtin_amdgcn_rcpf(l_run[qt]);
        size_t rowb = (seqbase + qi_base + qt * 16 + l15) * 1024 + h * 64;
#pragma unroll
        for (int dt = 0; dt < 4; ++dt) {
            int2 val = {pk_bf16(o[qt][dt][0] * rl, o[qt][dt][1] * rl),
                        pk_bf16(o[qt][dt][2] * rl, o[qt][dt][3] * rl)};
            *(int2*)(attn_out + rowb + dt * 16 + quad * 4) = val;
        }
    }
}

extern "C" void kernel_launch(void* const* d_in, const int* in_sizes, int n_in,
                              void* d_out, int out_size, void* d_ws, size_t ws_size,
                              hipStream_t stream) {
    const float* x     = (const float*)d_in[0];  // [4,4096,1024]
    const float* w_qkv = (const float*)d_in[1];  // [1024,3072]
    const float* w_out = (const float*)d_in[2];  // [1024,1024]
    float* out = (float*)d_out;                  // [4,4096,1024]

    unsigned short* xb    = (unsigned short*)d_ws;                 // 16384*1024
    unsigned short* wqkvT = xb    + (size_t)16384 * 1024;          // 3072*1024
    unsigned short* woutT = wqkvT + (size_t)3072 * 1024;           // 1024*1024
    unsigned short* qkv   = woutT + (size_t)1024 * 1024;           // 16384*3072
    unsigned short* attn  = qkv   + (size_t)16384 * 3072;          // 16384*1024

    cvt_x<<<16384, 256, 0, stream>>>(x, xb, 4194304);
    transpose_bf16<<<dim3(96, 32), 256, 0, stream>>>(w_qkv, wqkvT, 1024, 3072);
    transpose_bf16<<<dim3(32, 32), 256, 0, stream>>>(w_out, woutT, 1024, 1024);
    // QKV: M=16384, N=3072 -> 128x12 = 1536 tiles (1536 % 8 == 0)
    gemm_bt128<true><<<1536, 256, 0, stream>>>(xb, wqkvT, qkv, 16384, 3072, 1024, 12);
    attn_swin<<<dim3(32, 64), 256, 0, stream>>>(qkv, attn);
    // out-proj: M=16384, N=1024 -> 128x4 = 512 tiles (512 % 8 == 0)
    gemm_bt128<false><<<512, 256, 0, stream>>>(attn, woutT, out, 16384, 1024, 1024, 4);
}

// Round 6
// 350.719 us; speedup vs baseline: 1.0636x; 1.0636x over previous
//
#include <hip/hip_runtime.h>

typedef __attribute__((ext_vector_type(8))) short short8;
typedef __attribute__((ext_vector_type(4))) float floatx4;

// int-bridge casts (generic->AS1/AS3): LDS generic addr low 32 bits = LDS offset
#define AS1(p) ((const __attribute__((address_space(1))) void*)(uintptr_t)(p))
#define AS3(p) ((__attribute__((address_space(3))) void*)(unsigned int)(uintptr_t)(p))

__device__ __forceinline__ unsigned short f2bf(float f) {
    union { float f; unsigned int u; } v; v.f = f;
    unsigned int u = v.u;
    unsigned int r = (u + 0x7FFFu + ((u >> 16) & 1u)) >> 16;
    return (unsigned short)r;
}

__device__ __forceinline__ int pk_bf16(float a, float b) {
#if __has_builtin(__builtin_amdgcn_cvt_pk_bf16_f32)
    auto r = __builtin_amdgcn_cvt_pk_bf16_f32(a, b);
    int out; __builtin_memcpy(&out, &r, sizeof(int)); return out;
#else
    return (int)f2bf(a) | ((int)f2bf(b) << 16);
#endif
}

// ---------------- convert x (fp32 -> bf16), 4 elems/thread ----------------
__global__ __launch_bounds__(256) void cvt_x(const float* __restrict__ src,
                                             unsigned short* __restrict__ dst, int n4) {
    int i = blockIdx.x * blockDim.x + threadIdx.x;
    if (i < n4) {
        float4 v = ((const float4*)src)[i];
        int2 o = {pk_bf16(v.x, v.y), pk_bf16(v.z, v.w)};
        ((int2*)dst)[i] = o;
    }
}

// ------------- transpose + convert: src[R][C] fp32 -> dst[C][R] bf16 -------------
__global__ __launch_bounds__(256) void transpose_bf16(const float* __restrict__ src,
                                                      unsigned short* __restrict__ dst,
                                                      int R, int C) {
    __shared__ float tile[32][33];
    int c0 = blockIdx.x * 32, r0 = blockIdx.y * 32;
    int tc = threadIdx.x & 31, tr = (threadIdx.x >> 5) * 4;
#pragma unroll
    for (int i = 0; i < 4; ++i)
        tile[tr + i][tc] = src[(size_t)(r0 + tr + i) * C + c0 + tc];
    __syncthreads();
#pragma unroll
    for (int i = 0; i < 4; ++i)
        dst[(size_t)(c0 + tr + i) * R + r0 + tc] = f2bf(tile[tc][tr + i]);
}

// -------------- 128x256-tile multi-block-per-CU bf16 MFMA GEMM --------------
// (unchanged from round 4 -- ~830 TF plateau, best measured variant)
template <bool OUT_BF16>
__global__ __launch_bounds__(256, 2) void gemm_bt128(const unsigned short* __restrict__ A,
                                                     const unsigned short* __restrict__ Bt,
                                                     void* __restrict__ Cout,
                                                     int M, int N, int K, int nbx) {
    __shared__ unsigned short Asm[2][128 * 32];
    __shared__ unsigned short Bsm[2][256 * 32];

    const int tid = threadIdx.x;
    const int wn = tid >> 6, lane = tid & 63, quad = lane >> 4, l15 = lane & 15;

    const int nwg = (int)gridDim.x;
    const int q8 = nwg >> 3;
    const int wgid = (int)blockIdx.x;
    const int swz = (wgid & 7) * q8 + (wgid >> 3);
    const int bm = (swz / nbx) * 128;
    const int bn = (swz % nbx) * 256;

    floatx4 acc[8][4];
    const floatx4 z = {0.f, 0.f, 0.f, 0.f};
#pragma unroll
    for (int mi = 0; mi < 8; ++mi)
#pragma unroll
        for (int ni = 0; ni < 4; ++ni) acc[mi][ni] = z;

    const int dA0 = tid, dA1 = tid + 256;
    const int rA0 = dA0 >> 2, cA0 = ((dA0 & 3) ^ ((dA0 >> 3) & 3)) * 8;
    const int rA1 = dA1 >> 2, cA1 = ((dA1 & 3) ^ ((dA1 >> 3) & 3)) * 8;
    const unsigned short* Asrc0 = A + (size_t)(bm + rA0) * K + cA0;
    const unsigned short* Asrc1 = A + (size_t)(bm + rA1) * K + cA1;
    const unsigned short* Bsrc[4];
    int dB[4];
#pragma unroll
    for (int j = 0; j < 4; ++j) {
        dB[j] = tid + j * 256;
        const int r = dB[j] >> 2, c = ((dB[j] & 3) ^ ((dB[j] >> 3) & 3)) * 8;
        Bsrc[j] = Bt + (size_t)(bn + r) * K + c;
    }

    const int NT = K >> 5;

    auto stage = [&](int t) {
        const int s = t & 1, ko = t * 32;
        __builtin_amdgcn_global_load_lds(AS1(Asrc0 + ko), AS3(&Asm[s][dA0 * 8]), 16, 0, 0);
        __builtin_amdgcn_global_load_lds(AS1(Asrc1 + ko), AS3(&Asm[s][dA1 * 8]), 16, 0, 0);
#pragma unroll
        for (int j = 0; j < 4; ++j)
            __builtin_amdgcn_global_load_lds(AS1(Bsrc[j] + ko), AS3(&Bsm[s][dB[j] * 8]), 16, 0, 0);
    };

    const int qc = (quad ^ ((l15 >> 1) & 3)) * 8;
    const int brow = wn * 64 + l15;

    stage(0);
    asm volatile("s_waitcnt vmcnt(0)" ::: "memory");
    __builtin_amdgcn_s_barrier();

    for (int t = 0; t < NT; ++t) {
        const int s = t & 1;
        const unsigned short* Ap = Asm[s];
        const unsigned short* Bp = Bsm[s];
        if (t + 1 < NT) stage(t + 1);

        short8 b[4], a0[4], a1[4];
#pragma unroll
        for (int ni = 0; ni < 4; ++ni)
            b[ni] = *(const short8*)&Bp[(brow + ni * 16) * 32 + qc];
#pragma unroll
        for (int mi = 0; mi < 4; ++mi)
            a0[mi] = *(const short8*)&Ap[(mi * 16 + l15) * 32 + qc];
#pragma unroll
        for (int mi = 0; mi < 4; ++mi)
            a1[mi] = *(const short8*)&Ap[(64 + mi * 16 + l15) * 32 + qc];

        __builtin_amdgcn_s_setprio(1);
#pragma unroll
        for (int mi = 0; mi < 4; ++mi)
#pragma unroll
            for (int ni = 0; ni < 4; ++ni)
                acc[mi][ni] = __builtin_amdgcn_mfma_f32_16x16x32_bf16(b[ni], a0[mi], acc[mi][ni], 0, 0, 0);
#pragma unroll
        for (int mi = 0; mi < 4; ++mi)
#pragma unroll
            for (int ni = 0; ni < 4; ++ni)
                acc[4 + mi][ni] = __builtin_amdgcn_mfma_f32_16x16x32_bf16(b[ni], a1[mi], acc[4 + mi][ni], 0, 0, 0);
        __builtin_amdgcn_s_setprio(0);

        asm volatile("s_waitcnt vmcnt(0)" ::: "memory");
        __builtin_amdgcn_s_barrier();
    }

#pragma unroll
    for (int mi = 0; mi < 8; ++mi) {
        const size_t row = (size_t)(bm + mi * 16 + l15);
#pragma unroll
        for (int ni = 0; ni < 4; ++ni) {
            const size_t col = (size_t)(bn + wn * 64 + ni * 16 + quad * 4);
            if (OUT_BF16) {
                int2 val = {pk_bf16(acc[mi][ni][0], acc[mi][ni][1]),
                            pk_bf16(acc[mi][ni][2], acc[mi][ni][3])};
                *(int2*)((unsigned short*)Cout + row * N + col) = val;
            } else {
                *(float4*)((float*)Cout + row * N + col) = *(const float4*)&acc[mi][ni];
            }
        }
    }
}

// ---------------- sliding-window flash attention (S^T, 32q/wave) ----------------
// Grid (32 q-blocks of 128, 64 b*h). Block: 4 waves; wave w owns 32 queries.
// Wave-pair p = w>>1 active in chunks [p, p+4] of 6 (83% busy).
// S^T = K.Q^T; softmax stats per-lane (q=l15); P->A-frag via ds_bpermute.
// K/V double-buffered (stride 72: 2-way bank alias = free), reg-prefetched.
// ROUND 6 (from round-4 base): qt=0/1 chains MERGED -- each kf/vf LDS fragment
// is read ONCE and feeds both qt MFMAs (LDS frag reads per chunk 32 -> 16),
// and the two qt dependency chains (QK-MFMA, softmax tree, bpermute+PV)
// interleave as independent ILP (latency-bound at 3 waves/SIMD).  Per-qt
// arithmetic order unchanged -> bit-identical output.  T5 setprio around
// MFMA clusters (m191: +4-7% attn).
__global__ __launch_bounds__(256, 3) void attn_swin(const unsigned short* __restrict__ qkv,
                                                    unsigned short* __restrict__ attn_out) {
    __shared__ unsigned short Klds[2][64 * 72];
    __shared__ unsigned short Vtl[2][64 * 72];

    const int blk = blockIdx.x, bh = blockIdx.y;
    const int b = bh >> 4, h = bh & 15;
    const int tid = threadIdx.x;
    const int wave = tid >> 6, lane = tid & 63, quad = lane >> 4, l15 = lane & 15;
    const int pair = wave >> 1;            // diagonal band of the wave-pair
    const int qoff = (wave & 1) * 32;      // offset within the pair's 64-q band
    const int qi_base = blk * 128 + wave * 32;
    const size_t seqbase = (size_t)b * 4096;

    // Q fragments hoisted once (A-layout == B-layout of Q^T)
    short8 qf[2][2];
#pragma unroll
    for (int qt = 0; qt < 2; ++qt)
#pragma unroll
        for (int ks = 0; ks < 2; ++ks)
            qf[qt][ks] = *(const short8*)(qkv + (seqbase + qi_base + qt * 16 + l15) * 3072
                                          + h * 64 + ks * 32 + quad * 8);

    floatx4 o[2][4];  // [qt][dt]: lane holds O[q=qt*16+l15][d=dt*16+quad*4+r]
    const floatx4 z = {0.f, 0.f, 0.f, 0.f};
    float m_run[2], l_run[2];
#pragma unroll
    for (int qt = 0; qt < 2; ++qt) {
#pragma unroll
        for (int dt = 0; dt < 4; ++dt) o[qt][dt] = z;
        m_run[qt] = -1.0e30f; l_run[qt] = 0.f;
    }

    const int kwin0 = blk * 128 - 256;
    const int c0 = (blk >= 2) ? 0 : (4 - 2 * blk);
    const int cLo = pair, cHi = pair + 4;
    const int sk_key = tid >> 2, sk_g = (tid & 3) * 16;
    const int sv_key = tid & 63, sv_dg = (tid >> 6) * 16;
    const float SC = 0.18033688f;  // dh^-0.5 * log2(e)

    // bpermute lane addressing: src lane = (quad&1)*32 + (t>>1)*16 + l15
    const int addrA = (((quad & 1) << 5) + l15) << 2;
    const int addrB = addrA + 64;
    const bool hiq = quad >= 2;

    int4 kvreg[4];
    auto load_kv = [&](int k0) {
        const int4* sk = (const int4*)(qkv + (seqbase + k0 + sk_key) * 3072 + 1024 + h * 64 + sk_g);
        kvreg[0] = sk[0]; kvreg[1] = sk[1];
        const int4* sv = (const int4*)(qkv + (seqbase + k0 + sv_key) * 3072 + 2048 + h * 64 + sv_dg);
        kvreg[2] = sv[0]; kvreg[3] = sv[1];
    };
    auto write_kv = [&](int buf) {
        *(int4*)&Klds[buf][sk_key * 72 + sk_g]     = kvreg[0];
        *(int4*)&Klds[buf][sk_key * 72 + sk_g + 8] = kvreg[1];
        union { unsigned short s[16]; int4 q[2]; } t;
        t.q[0] = kvreg[2]; t.q[1] = kvreg[3];
#pragma unroll
        for (int i = 0; i < 16; ++i) Vtl[buf][(sv_dg + i) * 72 + sv_key] = t.s[i];
    };

    load_kv(kwin0 + c0 * 64);   // == key 0 for clipped blocks
    write_kv(0);

    for (int c = c0; c < 6; ++c) {
        const int buf = (c - c0) & 1;
        __syncthreads();
        if (c < 5) load_kv(kwin0 + (c + 1) * 64);  // prefetch overlaps compute

        if (c >= cLo && c <= cHi) {
            // ---- S^T = K.Q^T, both qt share each kf read ----
            floatx4 sT[2][4];
#pragma unroll
            for (int qt = 0; qt < 2; ++qt)
#pragma unroll
                for (int ni = 0; ni < 4; ++ni) sT[qt][ni] = z;
            __builtin_amdgcn_s_setprio(1);
#pragma unroll
            for (int ks = 0; ks < 2; ++ks) {
#pragma unroll
                for (int ni = 0; ni < 4; ++ni) {
                    short8 kf = *(const short8*)&Klds[buf][(ni * 16 + l15) * 72 + ks * 32 + quad * 8];
                    sT[0][ni] = __builtin_amdgcn_mfma_f32_16x16x32_bf16(kf, qf[0][ks], sT[0][ni], 0, 0, 0);
                    sT[1][ni] = __builtin_amdgcn_mfma_f32_16x16x32_bf16(kf, qf[1][ks], sT[1][ni], 0, 0, 0);
                }
            }
            __builtin_amdgcn_s_setprio(0);

            // ---- mask diagonal chunks (key j = ni*16+quad*4+r, query i64) ----
            if (c == cLo) {            // valid iff j >= i64+1
#pragma unroll
                for (int qt = 0; qt < 2; ++qt) {
                    const int i64 = qoff + qt * 16 + l15;
#pragma unroll
                    for (int ni = 0; ni < 4; ++ni) {
                        int jb = ni * 16 + quad * 4;
#pragma unroll
                        for (int r = 0; r < 4; ++r)
                            if (jb + r < i64 + 1) sT[qt][ni][r] = -3.0e38f;
                    }
                }
            } else if (c == cHi) {     // valid iff j <= i64
#pragma unroll
                for (int qt = 0; qt < 2; ++qt) {
                    const int i64 = qoff + qt * 16 + l15;
#pragma unroll
                    for (int ni = 0; ni < 4; ++ni) {
                        int jb = ni * 16 + quad * 4;
#pragma unroll
                        for (int r = 0; r < 4; ++r)
                            if (jb + r > i64) sT[qt][ni][r] = -3.0e38f;
                    }
                }
            }

            // ---- online softmax (log2 domain), qt chains interleaved ----
            float mx[2], mn[2], alpha[2], ls[2];
            int Pk[2][4][2];
#pragma unroll
            for (int qt = 0; qt < 2; ++qt) {
                mx[qt] = -3.0e38f;
#pragma unroll
                for (int ni = 0; ni < 4; ++ni)
#pragma unroll
                    for (int r = 0; r < 4; ++r) mx[qt] = fmaxf(mx[qt], sT[qt][ni][r]);
            }
#pragma unroll
            for (int qt = 0; qt < 2; ++qt) {
                mx[qt] = fmaxf(mx[qt], __shfl_xor(mx[qt], 16));
                mx[qt] = fmaxf(mx[qt], __shfl_xor(mx[qt], 32));
                mn[qt] = fmaxf(m_run[qt], mx[qt] * SC);
                alpha[qt] = __builtin_amdgcn_exp2f(m_run[qt] - mn[qt]);
                m_run[qt] = mn[qt];
                ls[qt] = 0.f;
            }
#pragma unroll
            for (int qt = 0; qt < 2; ++qt) {
#pragma unroll
                for (int ni = 0; ni < 4; ++ni) {
                    float p0 = __builtin_amdgcn_exp2f(fmaf(sT[qt][ni][0], SC, -mn[qt]));
                    float p1 = __builtin_amdgcn_exp2f(fmaf(sT[qt][ni][1], SC, -mn[qt]));
                    float p2 = __builtin_amdgcn_exp2f(fmaf(sT[qt][ni][2], SC, -mn[qt]));
                    float p3 = __builtin_amdgcn_exp2f(fmaf(sT[qt][ni][3], SC, -mn[qt]));
                    ls[qt] += (p0 + p1) + (p2 + p3);
                    Pk[qt][ni][0] = pk_bf16(p0, p1);
                    Pk[qt][ni][1] = pk_bf16(p2, p3);
                }
            }
#pragma unroll
            for (int qt = 0; qt < 2; ++qt) {
                ls[qt] += __shfl_xor(ls[qt], 16);
                ls[qt] += __shfl_xor(ls[qt], 32);
                l_run[qt] = l_run[qt] * alpha[qt] + ls[qt];
#pragma unroll
                for (int dt = 0; dt < 4; ++dt)
#pragma unroll
                    for (int r = 0; r < 4; ++r) o[qt][dt][r] *= alpha[qt];
            }

            // ---- V^T fragments once (shared by both qt) ----
            short8 vf[4][2];
#pragma unroll
            for (int dt = 0; dt < 4; ++dt)
#pragma unroll
                for (int ks = 0; ks < 2; ++ks)
                    vf[dt][ks] = *(const short8*)&Vtl[buf][(dt * 16 + l15) * 72 + ks * 32 + quad * 8];

            // ---- quad-permute P (C-layout) -> A-frag, then PV (both qt) ----
#pragma unroll
            for (int qt = 0; qt < 2; ++qt) {
#pragma unroll
                for (int ks = 0; ks < 2; ++ks) {
                    int a0 = __builtin_amdgcn_ds_bpermute(addrA, Pk[qt][2 * ks][0]);
                    int b0 = __builtin_amdgcn_ds_bpermute(addrA, Pk[qt][2 * ks + 1][0]);
                    int a1 = __builtin_amdgcn_ds_bpermute(addrA, Pk[qt][2 * ks][1]);
                    int b1 = __builtin_amdgcn_ds_bpermute(addrA, Pk[qt][2 * ks + 1][1]);
                    int a2 = __builtin_amdgcn_ds_bpermute(addrB, Pk[qt][2 * ks][0]);
                    int b2 = __builtin_amdgcn_ds_bpermute(addrB, Pk[qt][2 * ks + 1][0]);
                    int a3 = __builtin_amdgcn_ds_bpermute(addrB, Pk[qt][2 * ks][1]);
                    int b3 = __builtin_amdgcn_ds_bpermute(addrB, Pk[qt][2 * ks + 1][1]);
                    union { int i[4]; short8 v; } u;
                    u.i[0] = hiq ? b0 : a0;
                    u.i[1] = hiq ? b1 : a1;
                    u.i[2] = hiq ? b2 : a2;
                    u.i[3] = hiq ? b3 : a3;
                    __builtin_amdgcn_s_setprio(1);
#pragma unroll
                    for (int dt = 0; dt < 4; ++dt)
                        o[qt][dt] = __builtin_amdgcn_mfma_f32_16x16x32_bf16(vf[dt][ks], u.v, o[qt][dt], 0, 0, 0);
                    __builtin_amdgcn_s_setprio(0);
                }
            }
        }

        if (c < 5) write_kv(buf ^ 1);
    }

    // ---- epilogue ----
#pragma unroll
    for (int qt = 0; qt < 2; ++qt) {
        float rl = __builtin_amdgcn_rcpf(l_run[qt]);
        size_t rowb = (seqbase + qi_base + qt * 16 + l15) * 1024 + h * 64;
#pragma unroll
        for (int dt = 0; dt < 4; ++dt) {
            int2 val = {pk_bf16(o[qt][dt][0] * rl, o[qt][dt][1] * rl),
                        pk_bf16(o[qt][dt][2] * rl, o[qt][dt][3] * rl)};
            *(int2*)(attn_out + rowb + dt * 16 + quad * 4) = val;
        }
    }
}

extern "C" void kernel_launch(void* const* d_in, const int* in_sizes, int n_in,
                              void* d_out, int out_size, void* d_ws, size_t ws_size,
                              hipStream_t stream) {
    const float* x     = (const float*)d_in[0];  // [4,4096,1024]
    const float* w_qkv = (const float*)d_in[1];  // [1024,3072]
    const float* w_out = (const float*)d_in[2];  // [1024,1024]
    float* out = (float*)d_out;                  // [4,4096,1024]

    unsigned short* xb    = (unsigned short*)d_ws;                 // 16384*1024
    unsigned short* wqkvT = xb    + (size_t)16384 * 1024;          // 3072*1024
    unsigned short* woutT = wqkvT + (size_t)3072 * 1024;           // 1024*1024
    unsigned short* qkv   = woutT + (size_t)1024 * 1024;           // 16384*3072
    unsigned short* attn  = qkv   + (size_t)16384 * 3072;          // 16384*1024

    cvt_x<<<16384, 256, 0, stream>>>(x, xb, 4194304);
    transpose_bf16<<<dim3(96, 32), 256, 0, stream>>>(w_qkv, wqkvT, 1024, 3072);
    transpose_bf16<<<dim3(32, 32), 256, 0, stream>>>(w_out, woutT, 1024, 1024);
    // QKV: M=16384, N=3072 -> 128x12 = 1536 tiles (1536 % 8 == 0)
    gemm_bt128<true><<<1536, 256, 0, stream>>>(xb, wqkvT, qkv, 16384, 3072, 1024, 12);
    attn_swin<<<dim3(32, 64), 256, 0, stream>>>(qkv, attn);
    // out-proj: M=16384, N=1024 -> 128x4 = 512 tiles (512 % 8 == 0)
    gemm_bt128<false><<<512, 256, 0, stream>>>(attn, woutT, out, 16384, 1024, 1024, 4);
}